// Round 1
// baseline (254.464 us; speedup 1.0000x reference)
//
#include <hip/hip_runtime.h>
#include <hip/hip_bf16.h>

typedef __bf16 bf16;
typedef __attribute__((ext_vector_type(4)))  __bf16 bf16x4;
typedef __attribute__((ext_vector_type(8)))  __bf16 bf16x8;
typedef __attribute__((ext_vector_type(16))) float  f32x16;

#define B_   512
#define NC_  512
#define K_   4
#define S_   8
#define H_   128
#define D_   64
#define XROW (NC_ * K_)
#define NITER 16        // 512 items / (4 waves * 8 items/iter)

// pi: swap bits 2,3 of within-32 index (involution). Hidden dims stored
// physically permuted so the 32x32 MFMA C/D register layout of layer k IS
// the B-fragment layout of layer k+1 (r3/r5/r8-verified algebra).
static __device__ __forceinline__ int swap23(int v) {
    return (v & ~12) | ((v & 4) << 1) | ((v & 8) >> 1);
}

// Barrier-free restructure: each wave owns 32 batch-rows end-to-end
// (full H=128 layer-1, full K=128 layer-2 from its own hfo, full logits).
// No HX/LX exchange -> zero __syncthreads() in the main loop; waves run
// independently and hide each other's latency. Layer-2/3 done in two
// output-half phases (C0/C1 then C2/C3) to cap register pressure ~220.
__global__ __launch_bounds__(256, 2)
void jt_mlp_kernel(const int*   __restrict__ x,
                   const float* __restrict__ W1g, const float* __restrict__ b1g,
                   const float* __restrict__ W2g, const float* __restrict__ b2g,
                   const float* __restrict__ W3g, const float* __restrict__ b3g,
                   float* __restrict__ out)
{
    // Swizzled weights: element (row p, k) at p*rowlen + ch*8 + (k&7),
    //   W1: ch = (k>>3) ^ (p&7)
    //   W2: ch = (k>>3) ^ (p&15) ^ ((p&16)>>2)   (5th bit: kills the
    //       l31 vs l31+16 same-bank alias -> 8-access/bank minimum)
    __shared__ __align__(16) bf16 SW2[128 * 128];   // 32 KB
    __shared__ __align__(16) bf16 SWX[128 * 64];    // 16 KB: W1 (persists)
    __shared__ __align__(16) bf16 SW3[8 * 128];     // 2 KB

    const int tid  = threadIdx.x;
    const int lane = tid & 63;
    const int w    = tid >> 6;      // 0..3 (independent waves)
    const int l31  = lane & 31;
    const int lhi  = lane >> 5;
    const int kk   = l31 & 3;
    const int n    = blockIdx.x;    // clique (512 blocks, 2 blocks/CU)

    const float* W1p = W1g + (size_t)n * (D_ * H_);
    const float* W2p = W2g + (size_t)n * (H_ * H_);
    const float* W3p = W3g + (size_t)n * (H_ * S_);
    const float* b1p = b1g + n * H_;
    const float* b2p = b2g + n * H_;
    const float* b3p = b3g + n * S_;

    const int p31 = swap23(l31);
    const bf16 one = (bf16)1.0f, zero = (bf16)0.0f;

    // ============ stage weights into LDS (coalesced float4; r8-proven) ============
    // W1 -> SWX. k<8 rows carry +b1; root n==0 zeroes k<32 first.
    {
        const int c0 = (tid & 31) * 4;
        const int k0 = (tid >> 5) * 8;          // 0..56
        float rows[8][4];
#pragma unroll
        for (int i = 0; i < 8; ++i) {
            float4 t4 = *(const float4*)(W1p + (k0 + i) * H_ + c0);
            if (n == 0 && k0 < 32) t4 = make_float4(0.f, 0.f, 0.f, 0.f);
            rows[i][0] = t4.x; rows[i][1] = t4.y; rows[i][2] = t4.z; rows[i][3] = t4.w;
        }
        if (k0 == 0) {
            const float4 bb = *(const float4*)(b1p + c0);
#pragma unroll
            for (int i = 0; i < 8; ++i) {
                rows[i][0] += bb.x; rows[i][1] += bb.y;
                rows[i][2] += bb.z; rows[i][3] += bb.w;
            }
        }
#pragma unroll
        for (int j2 = 0; j2 < 4; ++j2) {
            const int c = c0 + j2;
            const int p = (c & ~31) | swap23(c & 31);
            const int ch = (k0 >> 3) ^ (p & 7);
            bf16x4 lo, hi;
#pragma unroll
            for (int i = 0; i < 4; ++i) {
                lo[i] = (bf16)rows[i][j2];
                hi[i] = (bf16)rows[4 + i][j2];
            }
            *(bf16x4*)&SWX[p * 64 + ch * 8 + 0] = lo;
            *(bf16x4*)&SWX[p * 64 + ch * 8 + 4] = hi;
        }
    }
    // W2 -> SW2 (5-bit swizzle)
    {
        const int c0 = (tid & 31) * 4;
        const int kbase = (tid >> 5) * 16;      // 0..112
#pragma unroll
        for (int hh = 0; hh < 2; ++hh) {
            const int k0 = kbase + hh * 8;
            float rows[8][4];
#pragma unroll
            for (int i = 0; i < 8; ++i) {
                const float4 t4 = *(const float4*)(W2p + (k0 + i) * H_ + c0);
                rows[i][0] = t4.x; rows[i][1] = t4.y; rows[i][2] = t4.z; rows[i][3] = t4.w;
            }
#pragma unroll
            for (int j2 = 0; j2 < 4; ++j2) {
                const int c = c0 + j2;
                const int p = (c & ~31) | swap23(c & 31);
                const int ch = (k0 >> 3) ^ (p & 15) ^ ((p & 16) >> 2);
                bf16x4 lo, hi;
#pragma unroll
                for (int i = 0; i < 4; ++i) {
                    lo[i] = (bf16)rows[i][j2];
                    hi[i] = (bf16)rows[4 + i][j2];
                }
                *(bf16x4*)&SW2[p * 128 + ch * 8 + 0] = lo;
                *(bf16x4*)&SW2[p * 128 + ch * 8 + 4] = hi;
            }
        }
    }
    // W3^T[s][k] -> SW3
    if (tid < 128) {
        const int s = tid >> 4, kc = tid & 15, k0 = kc * 8;
        float vv[8];
#pragma unroll
        for (int i = 0; i < 8; ++i) vv[i] = W3p[(k0 + i) * S_ + s];
        const int ch = kc ^ s;
        bf16x4 lo, hi;
#pragma unroll
        for (int i = 0; i < 4; ++i) { lo[i] = (bf16)vv[i]; hi[i] = (bf16)vv[4 + i]; }
        *(bf16x4*)&SW3[s * 128 + ch * 8 + 0] = lo;
        *(bf16x4*)&SW3[s * 128 + ch * 8 + 4] = hi;
    }
    __syncthreads();   // the ONLY barrier: staging -> everything else

    // ---- W1 fragments: ALL 128 H rows (4 row-groups x 4 k-chunks) ----
    bf16x8 w1f[4][4];
#pragma unroll
    for (int aa = 0; aa < 4; ++aa)
#pragma unroll
        for (int kt = 0; kt < 4; ++kt)
            w1f[aa][kt] = *(const bf16x8*)
                &SWX[(32 * aa + l31) * 64 + (((kt << 1) + lhi) ^ (l31 & 7)) * 8];

    const int s2 = l31 & 7;   // lanes 8..31 duplicate state rows (outputs unused)

    // ---- bias frags: b2 injected via rank-1 MFMA (layout-exact) ----
    bf16x8 w2b[4], onef;
#pragma unroll
    for (int j = 0; j < 8; ++j) onef[j] = zero;
    onef[0] = lhi ? zero : one;
#pragma unroll
    for (int aa = 0; aa < 4; ++aa) {
#pragma unroll
        for (int j = 0; j < 8; ++j) w2b[aa][j] = zero;
        w2b[aa][0] = lhi ? zero : (bf16)b2p[32 * aa + p31];
    }
    const float4 b3q = *(const float4*)(b3p + 4 * lhi);

    f32x16 zf;
#pragma unroll
    for (int i = 0; i < 16; ++i) zf[i] = 0.f;

    // -------- x prefetch --------
    const int itbase = w * 8 + (l31 >> 2);
    int4 xo_c, xp_c;
    {
        const int* xb = x + (size_t)itbase * XROW + n * K_;
        xo_c = *(const int4*)xb;
        xp_c = (n > 0) ? *(const int4*)(xb - K_) : make_int4(0, 0, 0, 0);
    }

    const int swz = (l31 & 15) ^ ((l31 & 16) >> 2);
    const int pr0 = (     l31) * 128;
    const int pr1 = (32 + l31) * 128;
    const int pr2 = (64 + l31) * 128;
    const int pr3 = (96 + l31) * 128;

#pragma unroll 1
    for (int c = 0; c < NITER; ++c) {
        const int item = itbase + c * 32;
        const int4 xo = xo_c, xp = xp_c;
        if (c < NITER - 1) {
            const int* xb = x + (size_t)(item + 32) * XROW + n * K_;
            xo_c = *(const int4*)xb;
            xp_c = (n > 0) ? *(const int4*)(xb - K_) : make_int4(0, 0, 0, 0);
        }

        // ---- one-hot selectors (r3/r5-proven) ----
        int sel[4];
        sel[0] = (n > 0) ? (lhi ? xp.y : xp.x) : (lhi ? -1 : 0);
        sel[1] = (n > 0) ? (lhi ? xp.w : xp.z) : -1;
        sel[2] = (kk > (lhi ? 1 : 0)) ? (lhi ? xo.y : xo.x) : -1;
        sel[3] = (kk > (lhi ? 3 : 2)) ? (lhi ? xo.w : xo.z) : -1;

        // ---- layer 1: full H in-wave (4 acc chains) ----
        f32x16 A0 = zf, A1 = zf, A2 = zf, A3 = zf;
#pragma unroll
        for (int kt = 0; kt < 4; ++kt) {
            bf16x8 bf1;
#pragma unroll
            for (int j = 0; j < 8; ++j) bf1[j] = (sel[kt] == j) ? one : zero;
            A0 = __builtin_amdgcn_mfma_f32_32x32x16_bf16(w1f[0][kt], bf1, A0, 0, 0, 0);
            A1 = __builtin_amdgcn_mfma_f32_32x32x16_bf16(w1f[1][kt], bf1, A1, 0, 0, 0);
            A2 = __builtin_amdgcn_mfma_f32_32x32x16_bf16(w1f[2][kt], bf1, A2, 0, 0, 0);
            A3 = __builtin_amdgcn_mfma_f32_32x32x16_bf16(w1f[3][kt], bf1, A3, 0, 0, 0);
        }

        // ---- extract all 8 h1 B-frags (chained layout); no exchange ----
        bf16x8 hfo[8];
#pragma unroll
        for (int t = 0; t < 8; ++t) {
            const f32x16& Sa = (t < 2) ? A0 : (t < 4) ? A1 : (t < 6) ? A2 : A3;
#pragma unroll
            for (int j = 0; j < 8; ++j)
                hfo[t][j] = (bf16)fmaxf(Sa[8 * (t & 1) + j], 0.f);
        }

        f32x16 L = zf;

        // ---- layer 2/3, phase A: output rows 0..63 ----
        {
            f32x16 C0 = zf, C1 = zf;
#pragma unroll
            for (int q = 0; q < 8; ++q) {
                const int chunk = ((q << 1) + lhi) ^ swz;
                const bf16x8 f0 = *(const bf16x8*)&SW2[pr0 + chunk * 8];
                const bf16x8 f1 = *(const bf16x8*)&SW2[pr1 + chunk * 8];
                C0 = __builtin_amdgcn_mfma_f32_32x32x16_bf16(f0, hfo[q], C0, 0, 0, 0);
                C1 = __builtin_amdgcn_mfma_f32_32x32x16_bf16(f1, hfo[q], C1, 0, 0, 0);
            }
            C0 = __builtin_amdgcn_mfma_f32_32x32x16_bf16(w2b[0], onef, C0, 0, 0, 0);
            C1 = __builtin_amdgcn_mfma_f32_32x32x16_bf16(w2b[1], onef, C1, 0, 0, 0);
#pragma unroll
            for (int q = 0; q < 4; ++q) {
                bf16x8 hg;
                const f32x16& Sc = (q < 2) ? C0 : C1;
#pragma unroll
                for (int j = 0; j < 8; ++j)
                    hg[j] = (bf16)fmaxf(Sc[8 * (q & 1) + j], 0.f);
                const bf16x8 w3q = *(const bf16x8*)
                    &SW3[s2 * 128 + (((q << 1) + lhi) ^ s2) * 8];
                L = __builtin_amdgcn_mfma_f32_32x32x16_bf16(w3q, hg, L, 0, 0, 0);
            }
        }
        // ---- layer 2/3, phase B: output rows 64..127 ----
        {
            f32x16 C2 = zf, C3 = zf;
#pragma unroll
            for (int q = 0; q < 8; ++q) {
                const int chunk = ((q << 1) + lhi) ^ swz;
                const bf16x8 f2 = *(const bf16x8*)&SW2[pr2 + chunk * 8];
                const bf16x8 f3 = *(const bf16x8*)&SW2[pr3 + chunk * 8];
                C2 = __builtin_amdgcn_mfma_f32_32x32x16_bf16(f2, hfo[q], C2, 0, 0, 0);
                C3 = __builtin_amdgcn_mfma_f32_32x32x16_bf16(f3, hfo[q], C3, 0, 0, 0);
            }
            C2 = __builtin_amdgcn_mfma_f32_32x32x16_bf16(w2b[2], onef, C2, 0, 0, 0);
            C3 = __builtin_amdgcn_mfma_f32_32x32x16_bf16(w2b[3], onef, C3, 0, 0, 0);
#pragma unroll
            for (int q = 4; q < 8; ++q) {
                bf16x8 hg;
                const f32x16& Sc = (q < 6) ? C2 : C3;
#pragma unroll
                for (int j = 0; j < 8; ++j)
                    hg[j] = (bf16)fmaxf(Sc[8 * (q & 1) + j], 0.f);
                const bf16x8 w3q = *(const bf16x8*)
                    &SW3[s2 * 128 + (((q << 1) + lhi) ^ s2) * 8];
                L = __builtin_amdgcn_mfma_f32_32x32x16_bf16(w3q, hg, L, 0, 0, 0);
            }
        }

        // ---- epilogue: fully in-wave (full K accumulated; no LX) ----
        {
            const float Ls0 = L[0] + b3q.x;
            const float Ls1 = L[1] + b3q.y;
            const float Ls2 = L[2] + b3q.z;
            const float Ls3 = L[3] + b3q.w;

            float m4 = fmaxf(fmaxf(Ls0, Ls1), fmaxf(Ls2, Ls3));
            const float mm = fmaxf(m4, __shfl_xor(m4, 32));
            float e = __expf(Ls0 - mm) + __expf(Ls1 - mm) +
                      __expf(Ls2 - mm) + __expf(Ls3 - mm);
            const float ssum = e + __shfl_xor(e, 32);

            const int xs = (kk & 2) ? ((kk & 1) ? xo.w : xo.z)
                                    : ((kk & 1) ? xo.y : xo.x);
            const float own = (xs & 2) ? ((xs & 1) ? Ls3 : Ls2)
                                       : ((xs & 1) ? Ls1 : Ls0);
            const float oth = __shfl_xor(own, 32);
            const float obs = ((xs >> 2) == lhi) ? own : oth;
            float lp = obs - mm - __logf(ssum);
            lp += __shfl_xor(lp, 1);
            lp += __shfl_xor(lp, 2);
            if (lhi == 0 && kk == 0)
                out[(size_t)item * NC_ + n] = lp;
        }
    }
}

extern "C" void kernel_launch(void* const* d_in, const int* in_sizes, int n_in,
                              void* d_out, int out_size, void* d_ws, size_t ws_size,
                              hipStream_t stream) {
    const int*   x  = (const int*)d_in[0];
    const float* W1 = (const float*)d_in[1];
    const float* b1 = (const float*)d_in[2];
    const float* W2 = (const float*)d_in[3];
    const float* b2 = (const float*)d_in[4];
    const float* W3 = (const float*)d_in[5];
    const float* b3 = (const float*)d_in[6];
    float* out = (float*)d_out;
    jt_mlp_kernel<<<dim3(NC_), 256, 0, stream>>>(x, W1, b1, W2, b2, W3, b3, out);
}

// Round 2
// 247.079 us; speedup vs baseline: 1.0299x; 1.0299x over previous
//
#include <hip/hip_runtime.h>
#include <hip/hip_bf16.h>

typedef __bf16 bf16;
typedef __attribute__((ext_vector_type(4)))  __bf16 bf16x4;
typedef __attribute__((ext_vector_type(8)))  __bf16 bf16x8;
typedef __attribute__((ext_vector_type(16))) float  f32x16;

#define B_   512
#define NC_  512
#define K_   4
#define S_   8
#define H_   128
#define D_   64
#define XROW (NC_ * K_)
#define NITER 16        // 512 items / (4 waves * 8 items/iter)

// pi: swap bits 2,3 of within-32 index (involution). Hidden dims stored
// physically permuted so the 32x32 MFMA C/D register layout of layer k IS
// the B-fragment layout of layer k+1 (r3/r5/r8-verified algebra).
static __device__ __forceinline__ int swap23(int v) {
    return (v & ~12) | ((v & 4) << 1) | ((v & 8) >> 1);
}

// Barrier-free structure (round-1), spill-fixed (round-2): each wave owns 32
// batch-rows end-to-end; zero __syncthreads() in the main loop. W1 fragments
// are STREAMED from LDS per iteration (not register-resident) -> arch-VGPR
// demand ~80 instead of ~130+, eliminating the round-1 scratch spills
// (WRITE_SIZE 61 MB -> ~9 MB). Total LDS b128 traffic equals the old
// pair-split kernel (56/iter x 16 = 28/iter x 32).
__global__ __launch_bounds__(256, 2)
void jt_mlp_kernel(const int*   __restrict__ x,
                   const float* __restrict__ W1g, const float* __restrict__ b1g,
                   const float* __restrict__ W2g, const float* __restrict__ b2g,
                   const float* __restrict__ W3g, const float* __restrict__ b3g,
                   float* __restrict__ out)
{
    // Swizzled weights: element (row p, k) at p*rowlen + ch*8 + (k&7),
    //   W1: ch = (k>>3) ^ (p&7)
    //   W2: ch = (k>>3) ^ (p&15) ^ ((p&16)>>2)   (5th bit: kills the
    //       l31 vs l31+16 same-bank alias -> 8-access/bank minimum)
    __shared__ __align__(16) bf16 SW2[128 * 128];   // 32 KB
    __shared__ __align__(16) bf16 SWX[128 * 64];    // 16 KB: W1 (persists)
    __shared__ __align__(16) bf16 SW3[8 * 128];     // 2 KB

    const int tid  = threadIdx.x;
    const int lane = tid & 63;
    const int w    = tid >> 6;      // 0..3 (independent waves)
    const int l31  = lane & 31;
    const int lhi  = lane >> 5;
    const int kk   = l31 & 3;
    const int n    = blockIdx.x;    // clique (512 blocks, 2 blocks/CU)

    const float* W1p = W1g + (size_t)n * (D_ * H_);
    const float* W2p = W2g + (size_t)n * (H_ * H_);
    const float* W3p = W3g + (size_t)n * (H_ * S_);
    const float* b1p = b1g + n * H_;
    const float* b2p = b2g + n * H_;
    const float* b3p = b3g + n * S_;

    const int p31 = swap23(l31);
    const bf16 one = (bf16)1.0f, zero = (bf16)0.0f;

    // ============ stage weights into LDS (coalesced float4; r8-proven) ============
    // W1 -> SWX. k<8 rows carry +b1; root n==0 zeroes k<32 first.
    {
        const int c0 = (tid & 31) * 4;
        const int k0 = (tid >> 5) * 8;          // 0..56
        float rows[8][4];
#pragma unroll
        for (int i = 0; i < 8; ++i) {
            float4 t4 = *(const float4*)(W1p + (k0 + i) * H_ + c0);
            if (n == 0 && k0 < 32) t4 = make_float4(0.f, 0.f, 0.f, 0.f);
            rows[i][0] = t4.x; rows[i][1] = t4.y; rows[i][2] = t4.z; rows[i][3] = t4.w;
        }
        if (k0 == 0) {
            const float4 bb = *(const float4*)(b1p + c0);
#pragma unroll
            for (int i = 0; i < 8; ++i) {
                rows[i][0] += bb.x; rows[i][1] += bb.y;
                rows[i][2] += bb.z; rows[i][3] += bb.w;
            }
        }
#pragma unroll
        for (int j2 = 0; j2 < 4; ++j2) {
            const int c = c0 + j2;
            const int p = (c & ~31) | swap23(c & 31);
            const int ch = (k0 >> 3) ^ (p & 7);
            bf16x4 lo, hi;
#pragma unroll
            for (int i = 0; i < 4; ++i) {
                lo[i] = (bf16)rows[i][j2];
                hi[i] = (bf16)rows[4 + i][j2];
            }
            *(bf16x4*)&SWX[p * 64 + ch * 8 + 0] = lo;
            *(bf16x4*)&SWX[p * 64 + ch * 8 + 4] = hi;
        }
    }
    // W2 -> SW2 (5-bit swizzle)
    {
        const int c0 = (tid & 31) * 4;
        const int kbase = (tid >> 5) * 16;      // 0..112
#pragma unroll
        for (int hh = 0; hh < 2; ++hh) {
            const int k0 = kbase + hh * 8;
            float rows[8][4];
#pragma unroll
            for (int i = 0; i < 8; ++i) {
                const float4 t4 = *(const float4*)(W2p + (k0 + i) * H_ + c0);
                rows[i][0] = t4.x; rows[i][1] = t4.y; rows[i][2] = t4.z; rows[i][3] = t4.w;
            }
#pragma unroll
            for (int j2 = 0; j2 < 4; ++j2) {
                const int c = c0 + j2;
                const int p = (c & ~31) | swap23(c & 31);
                const int ch = (k0 >> 3) ^ (p & 15) ^ ((p & 16) >> 2);
                bf16x4 lo, hi;
#pragma unroll
                for (int i = 0; i < 4; ++i) {
                    lo[i] = (bf16)rows[i][j2];
                    hi[i] = (bf16)rows[4 + i][j2];
                }
                *(bf16x4*)&SW2[p * 128 + ch * 8 + 0] = lo;
                *(bf16x4*)&SW2[p * 128 + ch * 8 + 4] = hi;
            }
        }
    }
    // W3^T[s][k] -> SW3
    if (tid < 128) {
        const int s = tid >> 4, kc = tid & 15, k0 = kc * 8;
        float vv[8];
#pragma unroll
        for (int i = 0; i < 8; ++i) vv[i] = W3p[(k0 + i) * S_ + s];
        const int ch = kc ^ s;
        bf16x4 lo, hi;
#pragma unroll
        for (int i = 0; i < 4; ++i) { lo[i] = (bf16)vv[i]; hi[i] = (bf16)vv[4 + i]; }
        *(bf16x4*)&SW3[s * 128 + ch * 8 + 0] = lo;
        *(bf16x4*)&SW3[s * 128 + ch * 8 + 4] = hi;
    }
    __syncthreads();   // the ONLY barrier: staging -> everything else

    const int s2 = l31 & 7;   // lanes 8..31 duplicate state rows (outputs unused)

    // ---- bias frags: b2 injected via rank-1 MFMA (layout-exact) ----
    bf16x8 w2b[4], onef;
#pragma unroll
    for (int j = 0; j < 8; ++j) onef[j] = zero;
    onef[0] = lhi ? zero : one;
#pragma unroll
    for (int aa = 0; aa < 4; ++aa) {
#pragma unroll
        for (int j = 0; j < 8; ++j) w2b[aa][j] = zero;
        w2b[aa][0] = lhi ? zero : (bf16)b2p[32 * aa + p31];
    }
    const float4 b3q = *(const float4*)(b3p + 4 * lhi);

    f32x16 zf;
#pragma unroll
    for (int i = 0; i < 16; ++i) zf[i] = 0.f;

    // -------- x prefetch --------
    const int itbase = w * 8 + (l31 >> 2);
    int4 xo_c, xp_c;
    {
        const int* xb = x + (size_t)itbase * XROW + n * K_;
        xo_c = *(const int4*)xb;
        xp_c = (n > 0) ? *(const int4*)(xb - K_) : make_int4(0, 0, 0, 0);
    }

    const int swz = (l31 & 15) ^ ((l31 & 16) >> 2);
    const int w1x = l31 & 7;
    const int w1r = l31 * 64;
    const int pr0 = (     l31) * 128;
    const int pr1 = (32 + l31) * 128;
    const int pr2 = (64 + l31) * 128;
    const int pr3 = (96 + l31) * 128;

#pragma unroll 1
    for (int c = 0; c < NITER; ++c) {
        const int item = itbase + c * 32;
        const int4 xo = xo_c, xp = xp_c;
        if (c < NITER - 1) {
            const int* xb = x + (size_t)(item + 32) * XROW + n * K_;
            xo_c = *(const int4*)xb;
            xp_c = (n > 0) ? *(const int4*)(xb - K_) : make_int4(0, 0, 0, 0);
        }

        // ---- one-hot selectors (r3/r5-proven) ----
        int sel[4];
        sel[0] = (n > 0) ? (lhi ? xp.y : xp.x) : (lhi ? -1 : 0);
        sel[1] = (n > 0) ? (lhi ? xp.w : xp.z) : -1;
        sel[2] = (kk > (lhi ? 1 : 0)) ? (lhi ? xo.y : xo.x) : -1;
        sel[3] = (kk > (lhi ? 3 : 2)) ? (lhi ? xo.w : xo.z) : -1;

        // ---- layer 1: full H in-wave; W1 frags streamed from LDS ----
        f32x16 A0 = zf, A1 = zf, A2 = zf, A3 = zf;
#pragma unroll
        for (int kt = 0; kt < 4; ++kt) {
            bf16x8 bf1;
#pragma unroll
            for (int j = 0; j < 8; ++j) bf1[j] = (sel[kt] == j) ? one : zero;
            const int ch8 = (((kt << 1) + lhi) ^ w1x) * 8;
            const bf16x8 wf0 = *(const bf16x8*)&SWX[w1r +        ch8];
            const bf16x8 wf1 = *(const bf16x8*)&SWX[w1r + 2048 + ch8];
            const bf16x8 wf2 = *(const bf16x8*)&SWX[w1r + 4096 + ch8];
            const bf16x8 wf3 = *(const bf16x8*)&SWX[w1r + 6144 + ch8];
            A0 = __builtin_amdgcn_mfma_f32_32x32x16_bf16(wf0, bf1, A0, 0, 0, 0);
            A1 = __builtin_amdgcn_mfma_f32_32x32x16_bf16(wf1, bf1, A1, 0, 0, 0);
            A2 = __builtin_amdgcn_mfma_f32_32x32x16_bf16(wf2, bf1, A2, 0, 0, 0);
            A3 = __builtin_amdgcn_mfma_f32_32x32x16_bf16(wf3, bf1, A3, 0, 0, 0);
        }

        // ---- extract all 8 h1 B-frags (chained layout); no exchange ----
        bf16x8 hfo[8];
#pragma unroll
        for (int t = 0; t < 8; ++t) {
            const f32x16& Sa = (t < 2) ? A0 : (t < 4) ? A1 : (t < 6) ? A2 : A3;
#pragma unroll
            for (int j = 0; j < 8; ++j)
                hfo[t][j] = (bf16)fmaxf(Sa[8 * (t & 1) + j], 0.f);
        }

        f32x16 L = zf;

        // ---- layer 2/3, phase A: output rows 0..63 ----
        {
            f32x16 C0 = zf, C1 = zf;
#pragma unroll
            for (int q = 0; q < 8; ++q) {
                const int chunk = ((q << 1) + lhi) ^ swz;
                const bf16x8 f0 = *(const bf16x8*)&SW2[pr0 + chunk * 8];
                const bf16x8 f1 = *(const bf16x8*)&SW2[pr1 + chunk * 8];
                C0 = __builtin_amdgcn_mfma_f32_32x32x16_bf16(f0, hfo[q], C0, 0, 0, 0);
                C1 = __builtin_amdgcn_mfma_f32_32x32x16_bf16(f1, hfo[q], C1, 0, 0, 0);
            }
            C0 = __builtin_amdgcn_mfma_f32_32x32x16_bf16(w2b[0], onef, C0, 0, 0, 0);
            C1 = __builtin_amdgcn_mfma_f32_32x32x16_bf16(w2b[1], onef, C1, 0, 0, 0);
#pragma unroll
            for (int q = 0; q < 4; ++q) {
                bf16x8 hg;
                const f32x16& Sc = (q < 2) ? C0 : C1;
#pragma unroll
                for (int j = 0; j < 8; ++j)
                    hg[j] = (bf16)fmaxf(Sc[8 * (q & 1) + j], 0.f);
                const bf16x8 w3q = *(const bf16x8*)
                    &SW3[s2 * 128 + (((q << 1) + lhi) ^ s2) * 8];
                L = __builtin_amdgcn_mfma_f32_32x32x16_bf16(w3q, hg, L, 0, 0, 0);
            }
        }
        // ---- layer 2/3, phase B: output rows 64..127 ----
        {
            f32x16 C2 = zf, C3 = zf;
#pragma unroll
            for (int q = 0; q < 8; ++q) {
                const int chunk = ((q << 1) + lhi) ^ swz;
                const bf16x8 f2 = *(const bf16x8*)&SW2[pr2 + chunk * 8];
                const bf16x8 f3 = *(const bf16x8*)&SW2[pr3 + chunk * 8];
                C2 = __builtin_amdgcn_mfma_f32_32x32x16_bf16(f2, hfo[q], C2, 0, 0, 0);
                C3 = __builtin_amdgcn_mfma_f32_32x32x16_bf16(f3, hfo[q], C3, 0, 0, 0);
            }
            C2 = __builtin_amdgcn_mfma_f32_32x32x16_bf16(w2b[2], onef, C2, 0, 0, 0);
            C3 = __builtin_amdgcn_mfma_f32_32x32x16_bf16(w2b[3], onef, C3, 0, 0, 0);
#pragma unroll
            for (int q = 4; q < 8; ++q) {
                bf16x8 hg;
                const f32x16& Sc = (q < 6) ? C2 : C3;
#pragma unroll
                for (int j = 0; j < 8; ++j)
                    hg[j] = (bf16)fmaxf(Sc[8 * (q & 1) + j], 0.f);
                const bf16x8 w3q = *(const bf16x8*)
                    &SW3[s2 * 128 + (((q << 1) + lhi) ^ s2) * 8];
                L = __builtin_amdgcn_mfma_f32_32x32x16_bf16(w3q, hg, L, 0, 0, 0);
            }
        }

        // ---- epilogue: fully in-wave (full K accumulated; no LX) ----
        {
            const float Ls0 = L[0] + b3q.x;
            const float Ls1 = L[1] + b3q.y;
            const float Ls2 = L[2] + b3q.z;
            const float Ls3 = L[3] + b3q.w;

            float m4 = fmaxf(fmaxf(Ls0, Ls1), fmaxf(Ls2, Ls3));
            const float mm = fmaxf(m4, __shfl_xor(m4, 32));
            float e = __expf(Ls0 - mm) + __expf(Ls1 - mm) +
                      __expf(Ls2 - mm) + __expf(Ls3 - mm);
            const float ssum = e + __shfl_xor(e, 32);

            const int xs = (kk & 2) ? ((kk & 1) ? xo.w : xo.z)
                                    : ((kk & 1) ? xo.y : xo.x);
            const float own = (xs & 2) ? ((xs & 1) ? Ls3 : Ls2)
                                       : ((xs & 1) ? Ls1 : Ls0);
            const float oth = __shfl_xor(own, 32);
            const float obs = ((xs >> 2) == lhi) ? own : oth;
            float lp = obs - mm - __logf(ssum);
            lp += __shfl_xor(lp, 1);
            lp += __shfl_xor(lp, 2);
            if (lhi == 0 && kk == 0)
                out[(size_t)item * NC_ + n] = lp;
        }
    }
}

extern "C" void kernel_launch(void* const* d_in, const int* in_sizes, int n_in,
                              void* d_out, int out_size, void* d_ws, size_t ws_size,
                              hipStream_t stream) {
    const int*   x  = (const int*)d_in[0];
    const float* W1 = (const float*)d_in[1];
    const float* b1 = (const float*)d_in[2];
    const float* W2 = (const float*)d_in[3];
    const float* b2 = (const float*)d_in[4];
    const float* W3 = (const float*)d_in[5];
    const float* b3 = (const float*)d_in[6];
    float* out = (float*)d_out;
    jt_mlp_kernel<<<dim3(NC_), 256, 0, stream>>>(x, W1, b1, W2, b2, W3, b3, out);
}